// Round 14
// baseline (425.682 us; speedup 1.0000x reference)
//
#include <hip/hip_runtime.h>
#include <stdint.h>

#define ROWS 150528              // 1024 * 147
#define QSCALE 0.17677669529663687f
#define L2E 1.44269504088896f

typedef __attribute__((ext_vector_type(8))) __bf16 bf16x8;
typedef __attribute__((ext_vector_type(4))) __bf16 bf16x4;
typedef __attribute__((ext_vector_type(4))) float f32x4;
typedef __attribute__((ext_vector_type(4))) float f4;

static __device__ __forceinline__ f32x4 mfma_bf16(bf16x8 a, bf16x8 b, f32x4 c) {
  return __builtin_amdgcn_mfma_f32_16x16x32_bf16(a, b, c, 0, 0, 0);
}

static __device__ __forceinline__ uint32_t pack_bf16(float a, float b) {
  uint16_t ux = __builtin_bit_cast(uint16_t, (__bf16)a);
  uint16_t uy = __builtin_bit_cast(uint16_t, (__bf16)b);
  return (uint32_t)ux | ((uint32_t)uy << 16);
}

// ---- convert 4 f32 weights -> bf16 in one launch: grid (36, 4) ----
__global__ void cvt4(const float* s0, const float* s1, const float* s2, const float* s3,
                     __bf16* d0, __bf16* d1, __bf16* d2, __bf16* d3) {
  const int y = blockIdx.y;
  const float* s = y == 0 ? s0 : y == 1 ? s1 : y == 2 ? s2 : s3;
  __bf16* d = y == 0 ? d0 : y == 1 ? d1 : y == 2 ? d2 : d3;
  int i = blockIdx.x * 256 + threadIdx.x;        // 9216 float4 groups
  f4 v = ((const f4*)s)[i];
  bf16x4 b;
  b[0] = (__bf16)v[0]; b[1] = (__bf16)v[1]; b[2] = (__bf16)v[2]; b[3] = (__bf16)v[3];
  ((bf16x4*)d)[i] = b;
}

// ---- precompute l2e*(mask + rel-pos bias): grid (64, 6); rows stride 57 ----
__global__ void bmpre(const float* __restrict__ maskp, const float* __restrict__ btab,
                      float* __restrict__ bmall) {
  const int win = blockIdx.x, h = blockIdx.y;
  float* dst = bmall + ((size_t)(win * 6 + h)) * 2800;
  for (int i = threadIdx.x; i < 2796; i += 256) {
    int q = i / 57, ke = i - q * 57;
    int k = ke >= 49 ? ke - 49 : ke;
    if (q > 48) q = 48;                            // elements 2793..2795 (pad)
    int qi = q / 7, qj = q - qi * 7, ki = k / 7, kj = k - ki * 7;
    int rel = (qi - ki + 6) * 13 + (qj - kj + 6);
    dst[i] = (maskp[win * 2401 + q * 49 + k] + btab[rel * 6 + h]) * L2E;
  }
}

// ---- GEMM v7: no-LDS, no-barrier, W-resident, wave-shared A ----
// Block = 4 waves, owns 64 rows (4 groups of 16). Wave w holds wf[3][6] for
// nt = w+4t (loaded ONCE -- round-13's 12x W-reload was the regression), and
// walks groups staggered (g = (w+gi)&3): wave 0's A-loads warm L1/L2 for waves
// 1-3 (same addresses; MSHRs merge). X has no cross-row reuse, so A-frags load
// direct from global: per kk the wave consumes 16 full 128B lines (f32) or 8
// (bf16 head-major). No LDS, no __syncthreads; ~120 VGPR at (256,2).
template<bool IN_F32, bool OUT_F32>
static __device__ __forceinline__
void gemm_direct(const void* __restrict__ Xv, const __bf16* __restrict__ Wb,
                 const float* __restrict__ bias, void* __restrict__ Ov, float scale)
{
  const int tid = threadIdx.x;
  const int wv = tid >> 6, lane = tid & 63, lr = lane & 15, lg = lane >> 4;
  const size_t blk0 = (size_t)blockIdx.x * 64;

  bf16x8 wf[3][6];
  float bcol[3];
  #pragma unroll
  for (int t = 0; t < 3; ++t) {
    const int nt = wv + 4 * t;
    const __bf16* wr = &Wb[(nt * 16 + lr) * 192 + lg * 8];
    #pragma unroll
    for (int kk = 0; kk < 6; ++kk) wf[t][kk] = *(const bf16x8*)&wr[kk * 32];
    bcol[t] = bias[nt * 16 + lr] * scale;
  }

  #pragma unroll
  for (int gi = 0; gi < 4; ++gi) {
    const int g = (wv + gi) & 3;                   // staggered group walk
    const size_t r0 = blk0 + g * 16;

    bf16x8 a[6];
    if (IN_F32) {
      const float* base = &((const float*)Xv)[(r0 + lr) * 192 + lg * 8];
      #pragma unroll
      for (int kk = 0; kk < 6; ++kk) {
        f4 p0 = *(const f4*)(base + kk * 32);
        f4 p1 = *(const f4*)(base + kk * 32 + 4);
        #pragma unroll
        for (int e = 0; e < 4; ++e) {
          a[kk][e]     = (__bf16)p0[e];
          a[kk][4 + e] = (__bf16)p1[e];
        }
      }
    } else {
      const __bf16* X = (const __bf16*)Xv;
      #pragma unroll
      for (int kk = 0; kk < 6; ++kk)
        a[kk] = *(const bf16x8*)&X[((size_t)kk * ROWS + r0 + lr) * 32 + lg * 8];
    }

    #pragma unroll
    for (int t = 0; t < 3; ++t) {
      f32x4 acc = {0.f, 0.f, 0.f, 0.f};
      #pragma unroll
      for (int kk = 0; kk < 6; ++kk) acc = mfma_bf16(a[kk], wf[t][kk], acc);
      const int nt = wv + 4 * t;
      const size_t grow = r0 + lg * 4;
      if (OUT_F32) {
        const int col = nt * 16 + lr;
        #pragma unroll
        for (int j = 0; j < 4; ++j)
          ((float*)Ov)[(grow + j) * 192 + col] = acc[j] * scale + bcol[t];
      } else {
        const int hh = nt >> 1, c32 = (nt & 1) * 16 + lr;
        #pragma unroll
        for (int j = 0; j < 4; ++j)
          ((__bf16*)Ov)[((size_t)hh * ROWS + grow + j) * 32 + c32] =
              (__bf16)(acc[j] * scale + bcol[t]);
      }
    }
  }
}

// fused QKV: grid (ROWS/64 = 2352, 3); y selects {q,k,v}
// Tripwires: FETCH >> 350MB -> L1/MSHR dedup failed; WRITE >> 175MB -> spill.
__global__ __launch_bounds__(256, 2)
void qkvgemm(const float* __restrict__ xq, const float* __restrict__ xk,
             const float* __restrict__ xv,
             const __bf16* __restrict__ wq, const __bf16* __restrict__ wk,
             const __bf16* __restrict__ wv,
             const float* __restrict__ bq, const float* __restrict__ bk,
             const float* __restrict__ bv,
             __bf16* __restrict__ oq, __bf16* __restrict__ ok,
             __bf16* __restrict__ ov)
{
  const int y = blockIdx.y;
  const float* x = y == 0 ? xq : y == 1 ? xk : xv;
  const __bf16* w = y == 0 ? wq : y == 1 ? wk : wv;
  const float* bi = y == 0 ? bq : y == 1 ? bk : bv;
  __bf16* o = y == 0 ? oq : y == 1 ? ok : ov;
  const float scale = y == 0 ? (QSCALE * L2E) : 1.f;
  gemm_direct<true, false>(x, w, bi, o, scale);
}

// proj: head-major bf16 in, row-major f32 out; grid 2352
__global__ __launch_bounds__(256, 2)
void projgemm(const __bf16* __restrict__ X, const __bf16* __restrict__ Wb,
              const float* __restrict__ bias, float* __restrict__ Ov)
{
  gemm_direct<false, true>(X, Wb, bias, Ov, 1.f);
}

// ---- attention v8 (round-10 proven): head-major I/O, bm in LDS, 5-wave ----
__global__ __launch_bounds__(320, 5)
void attn8(const __bf16* __restrict__ Q, const __bf16* __restrict__ K,
           const __bf16* __restrict__ V, __bf16* __restrict__ O,
           const float* __restrict__ bmall)
{
  __shared__ __align__(16) __bf16 Ks[160 * 40];   // 12800 B, permuted rows
  __shared__ __align__(16) __bf16 Vt[32 * 168];   // 10752 B, [d][key pad168]
  __shared__ __align__(16) float bm2[2796];       // 11184 B, stride 57 (odd)

  const int b = blockIdx.x, h = blockIdx.y;
  const int tid = threadIdx.x;
  const size_t hb = (size_t)h * ROWS + (size_t)b * 147;  // head-major row base
  const int wv = tid >> 6, lane = tid & 63;
  const int lr = lane & 15, lg = lane >> 4;

  // first Q fragment (mt=wv -> row <= 79, no clamp)
  bf16x8 qf = *(const bf16x8*)&Q[(hb + wv * 16 + lr) * 32 + lg * 8];

  // ---- staging (contiguous in head-major) ----
  {
    const f4* bsrc = (const f4*)(bmall + (size_t)((b & 63) * 6 + h) * 2800);
    for (int i = tid; i < 699; i += 320) ((f4*)bm2)[i] = bsrc[i];
  }
  for (int i = tid; i < 588; i += 320) {          // K -> permuted rows
    int k = i >> 2, c = i & 3;
    int phys = (k & ~31) | (((k >> 2) & 1) << 4) | (((k >> 3) & 3) << 2) | (k & 3);
    *(bf16x8*)&Ks[phys * 40 + c * 8] = *(const bf16x8*)&K[(hb + k) * 32 + c * 8];
  }
  for (int t = tid; t < 588; t += 320) {          // V transpose scatter
    int key = t >> 2, dblk = t & 3;
    bf16x8 v = *(const bf16x8*)&V[(hb + key) * 32 + dblk * 8];
    #pragma unroll
    for (int e = 0; e < 8; ++e) Vt[(dblk * 8 + e) * 168 + key] = v[e];
  }
  for (int i = tid; i < 32 * 13; i += 320) {      // zero key tail 147..159
    int d = i / 13, key = 147 + (i - (i / 13) * 13);
    Vt[d * 168 + key] = (__bf16)0.f;
  }
  __syncthreads();

  #pragma unroll
  for (int t = 0; t < 2; ++t) {
    const int mt = wv + 5 * t;                     // waves cover mt 0..9 exactly

    bf16x8 qn = qf;
    if (t == 0) {
      int qr = (wv + 5) * 16 + lr; if (qr > 146) qr = 146;
      qn = *(const bf16x8*)&Q[(hb + qr) * 32 + lg * 8];
    }

    int r = mt * 16 + lr;
    int q49 = r; if (q49 >= 98) q49 -= 98; if (q49 >= 49) q49 -= 49;
    const float* bmrow = &bm2[q49 * 57];

    f32x4 o0 = {0.f,0.f,0.f,0.f}, o1 = {0.f,0.f,0.f,0.f};
    float sum = 0.f;
    int kb = lg * 8;                               // (32s + 8lg) % 49, incremental
    #pragma unroll
    for (int s = 0; s < 5; ++s) {
      const f32x4 z = {0.f,0.f,0.f,0.f};
      f32x4 st0 = mfma_bf16(*(const bf16x8*)&Ks[(s * 32 + lr) * 40 + lg * 8], qf, z);
      f32x4 st1 = mfma_bf16(*(const bf16x8*)&Ks[(s * 32 + 16 + lr) * 40 + lg * 8], qf, z);
      const float* bp = bmrow + kb;                // 8 consecutive f32 (row has 57)
      #pragma unroll
      for (int j = 0; j < 4; ++j) { st0[j] += bp[j]; st1[j] += bp[4 + j]; }
      if (s == 4) {                                // keys 128+8lg+j / 132+8lg+j >= 147
        #pragma unroll
        for (int j = 0; j < 4; ++j) {
          if (lg * 8 + j >= 19) st0[j] = -1e30f;
          if (lg * 8 + j >= 15) st1[j] = -1e30f;
        }
      }
      #pragma unroll
      for (int j = 0; j < 4; ++j) { st0[j] = exp2f(st0[j]); sum += st0[j]; }
      #pragma unroll
      for (int j = 0; j < 4; ++j) { st1[j] = exp2f(st1[j]); sum += st1[j]; }
      union { bf16x8 v; uint32_t w[4]; } pu;
      pu.w[0] = pack_bf16(st0[0], st0[1]);
      pu.w[1] = pack_bf16(st0[2], st0[3]);
      pu.w[2] = pack_bf16(st1[0], st1[1]);
      pu.w[3] = pack_bf16(st1[2], st1[3]);
      bf16x8 v0 = *(const bf16x8*)&Vt[lr * 168 + s * 32 + lg * 8];
      bf16x8 v1 = *(const bf16x8*)&Vt[(16 + lr) * 168 + s * 32 + lg * 8];
      o0 = mfma_bf16(pu.v, v0, o0);
      o1 = mfma_bf16(pu.v, v1, o1);
      kb += 32; if (kb >= 49) kb -= 49;            // stays in [0,49)
    }
    sum += __shfl_xor(sum, 16);
    sum += __shfl_xor(sum, 32);
    const float rinv = 1.f / sum;
    #pragma unroll
    for (int j = 0; j < 4; ++j) {
      const int qa = mt * 16 + lg * 4 + j;
      const float rj = __shfl(rinv, lg * 4 + j);   // row sums live at lanes 0..15
      if (qa < 147) {
        const size_t base = (hb + qa) * 32;
        O[base + lr]      = (__bf16)(o0[j] * rj);
        O[base + 16 + lr] = (__bf16)(o1[j] * rj);
      }
    }
    qf = qn;
  }
}

extern "C" void kernel_launch(void* const* d_in, const int* in_sizes, int n_in,
                              void* d_out, int out_size, void* d_ws, size_t ws_size,
                              hipStream_t stream) {
  (void)in_sizes; (void)n_in; (void)out_size;
  const float* x_q  = (const float*)d_in[0];
  const float* x_k  = (const float*)d_in[1];
  const float* x_v  = (const float*)d_in[2];
  const float* maskp= (const float*)d_in[3];
  const float* q_w  = (const float*)d_in[4];
  const float* q_b  = (const float*)d_in[5];
  const float* k_w  = (const float*)d_in[6];
  const float* k_b  = (const float*)d_in[7];
  const float* v_w  = (const float*)d_in[8];
  const float* v_b  = (const float*)d_in[9];
  const float* p_w  = (const float*)d_in[10];
  const float* p_b  = (const float*)d_in[11];
  const float* btab = (const float*)d_in[12];

  char* ws = (char*)d_ws;
  // [bmall 4.3MB][4 weights][qb][kb][vb][ob?]
  float* bmall = (float*)ws;
  const size_t bmsz = (size_t)64 * 6 * 2800 * sizeof(float);   // 4,300,800
  char* wsp = ws + bmsz;
  const size_t wsz = 36864 * sizeof(__bf16);
  __bf16* wq  = (__bf16*)wsp;
  __bf16* wk  = (__bf16*)(wsp + wsz);
  __bf16* wvp = (__bf16*)(wsp + 2 * wsz);
  __bf16* wp  = (__bf16*)(wsp + 3 * wsz);
  char* bufs = wsp + 4 * wsz;
  const size_t sz = (size_t)ROWS * 192 * sizeof(__bf16);       // 57.8 MB each
  __bf16* qb = (__bf16*)bufs;
  __bf16* kb = (__bf16*)(bufs + sz);
  __bf16* vb = (__bf16*)(bufs + 2 * sz);
  const size_t need4 = bmsz + 4 * wsz + 4 * sz;
  __bf16* ob = (ws_size >= need4) ? (__bf16*)(bufs + 3 * sz) : qb;

  cvt4<<<dim3(36, 4), 256, 0, stream>>>(q_w, k_w, v_w, p_w, wq, wk, wvp, wp);
  bmpre<<<dim3(64, 6), 256, 0, stream>>>(maskp, btab, bmall);

  // q pre-scaled by 1/sqrt(hd) AND log2(e) (exp2-direct softmax downstream)
  qkvgemm<<<dim3(ROWS / 64, 3), 256, 0, stream>>>(x_q, x_k, x_v, wq, wk, wvp,
                                                  q_b, k_b, v_b, qb, kb, vb);

  attn8<<<dim3(1024, 6), 320, 0, stream>>>(qb, kb, vb, ob, bmall);

  projgemm<<<ROWS / 64, 256, 0, stream>>>(ob, wp, p_b, (float*)d_out);
}

// Round 15
// 259.082 us; speedup vs baseline: 1.6430x; 1.6430x over previous
//
#include <hip/hip_runtime.h>
#include <stdint.h>

#define ROWS 150528              // 1024 * 147
#define QSCALE 0.17677669529663687f
#define L2E 1.44269504088896f

typedef __attribute__((ext_vector_type(8))) __bf16 bf16x8;
typedef __attribute__((ext_vector_type(4))) __bf16 bf16x4;
typedef __attribute__((ext_vector_type(4))) float f32x4;
typedef __attribute__((ext_vector_type(4))) float f4;

static __device__ __forceinline__ f32x4 mfma_bf16(bf16x8 a, bf16x8 b, f32x4 c) {
  return __builtin_amdgcn_mfma_f32_16x16x32_bf16(a, b, c, 0, 0, 0);
}

static __device__ __forceinline__ uint32_t pack_bf16(float a, float b) {
  uint16_t ux = __builtin_bit_cast(uint16_t, (__bf16)a);
  uint16_t uy = __builtin_bit_cast(uint16_t, (__bf16)b);
  return (uint32_t)ux | ((uint32_t)uy << 16);
}

// ---- merged prep: blocks 0..143 = weight cvt (4 x 36), 144..527 = bias+mask ----
__global__ void prep(const float* __restrict__ q_w, const float* __restrict__ k_w,
                     const float* __restrict__ v_w, const float* __restrict__ p_w,
                     __bf16* __restrict__ wq, __bf16* __restrict__ wk,
                     __bf16* __restrict__ wv, __bf16* __restrict__ wp,
                     const float* __restrict__ maskp, const float* __restrict__ btab,
                     float* __restrict__ bmall) {
  const int bid = blockIdx.x;
  if (bid < 144) {
    const int y = bid / 36;
    const float* s = y == 0 ? q_w : y == 1 ? k_w : y == 2 ? v_w : p_w;
    __bf16* d = y == 0 ? wq : y == 1 ? wk : y == 2 ? wv : wp;
    int i = (bid % 36) * 256 + threadIdx.x;      // 9216 f4 groups per weight
    f4 v = ((const f4*)s)[i];
    bf16x4 b;
    b[0] = (__bf16)v[0]; b[1] = (__bf16)v[1]; b[2] = (__bf16)v[2]; b[3] = (__bf16)v[3];
    ((bf16x4*)d)[i] = b;
  } else {
    const int idx = bid - 144;                   // 384 = 64 win x 6 heads
    const int win = idx / 6, h = idx - win * 6;
    float* dst = bmall + ((size_t)idx) * 2800;
    for (int i = threadIdx.x; i < 2796; i += 256) {
      int q = i / 57, ke = i - q * 57;
      int k = ke >= 49 ? ke - 49 : ke;
      if (q > 48) q = 48;
      int qi = q / 7, qj = q - qi * 7, ki = k / 7, kj = k - ki * 7;
      int rel = (qi - ki + 6) * 13 + (qj - kj + 6);
      dst[i] = (maskp[win * 2401 + q * 49 + k] + btab[rel * 6 + h]) * L2E;
    }
  }
}

// ---- GEMM v8: 6 tiles/block, double-buffered LDS, ONE barrier/tile ----
// W-frags preloaded once (wf[3][6]); next tile's 12 f4 loads issued BEFORE
// compute and held in regs through it (launch_bounds(256,1) raises the VGPR
// cap so RA doesn't sink the loads -- round-10's (256,2)/108-reg version did
// sink them, defeating the prefetch). LDS write after compute, then barrier.
template<bool IN_F32, bool OUT_F32>
static __device__ __forceinline__
void gemm6t(const void* __restrict__ Xv, const __bf16* __restrict__ Wb,
            const float* __restrict__ bias, void* __restrict__ Ov, float scale,
            __bf16* Xs /* [2][64*200] */)
{
  const int tid = threadIdx.x;
  const int wv = tid >> 6, lane = tid & 63, lr = lane & 15, lg = lane >> 4;

  bf16x8 wf[3][6];
  float bcol[3];
  #pragma unroll
  for (int t = 0; t < 3; ++t) {
    const int nt = wv + 4 * t;
    const __bf16* wr = &Wb[(nt * 16 + lr) * 192 + lg * 8];
    #pragma unroll
    for (int kk = 0; kk < 6; ++kk) wf[t][kk] = *(const bf16x8*)&wr[kk * 32];
    bcol[t] = bias[nt * 16 + lr] * scale;
  }

  const size_t ti0 = (size_t)blockIdx.x * 6;

  // stage tile 0 -> Xs[0]
  if (IN_F32) {
    const f4* X4 = (const f4*)Xv + ti0 * 64 * 48;
    #pragma unroll
    for (int p = 0; p < 12; ++p) {
      int i = tid + p * 256;
      int r = i / 48, c = i % 48;
      f4 v = X4[i];
      bf16x4 bb;
      bb[0] = (__bf16)v[0]; bb[1] = (__bf16)v[1]; bb[2] = (__bf16)v[2]; bb[3] = (__bf16)v[3];
      *(bf16x4*)&Xs[r * 200 + c * 4] = bb;
    }
  } else {
    const __bf16* X = (const __bf16*)Xv;
    #pragma unroll
    for (int p = 0; p < 6; ++p) {
      int i = tid + p * 256;
      int r = i / 24, c8 = i % 24;
      int hh = c8 >> 2, sub = c8 & 3;
      *(bf16x8*)&Xs[r * 200 + c8 * 8] =
          *(const bf16x8*)&X[((size_t)hh * ROWS + ti0 * 64 + r) * 32 + sub * 8];
    }
  }
  __syncthreads();

  #pragma unroll
  for (int it = 0; it < 6; ++it) {
    __bf16* rb = &Xs[(it & 1) * 12800];
    const size_t row0 = (ti0 + it) * 64;

    // issue next tile's global loads NOW (held through compute; write later)
    f4 pf[12];
    bf16x8 pf8[6];
    if (it < 5) {
      if (IN_F32) {
        const f4* X4n = (const f4*)Xv + (row0 + 64) * 48;
        #pragma unroll
        for (int p = 0; p < 12; ++p) pf[p] = X4n[tid + p * 256];
      } else {
        const __bf16* X = (const __bf16*)Xv;
        #pragma unroll
        for (int p = 0; p < 6; ++p) {
          int i = tid + p * 256;
          int r = i / 24, c8 = i % 24;
          int hh = c8 >> 2, sub = c8 & 3;
          pf8[p] = *(const bf16x8*)&X[((size_t)hh * ROWS + row0 + 64 + r) * 32 + sub * 8];
        }
      }
    }

    // compute current tile (pf HBM latency hides under this)
    #pragma unroll
    for (int rg = 0; rg < 4; ++rg) {
      bf16x8 a[6];
      const __bf16* xr = &rb[(rg * 16 + lr) * 200 + lg * 8];
      #pragma unroll
      for (int kk = 0; kk < 6; ++kk) a[kk] = *(const bf16x8*)&xr[kk * 32];
      const size_t grow = row0 + rg * 16 + lg * 4;
      #pragma unroll
      for (int t = 0; t < 3; ++t) {
        f32x4 acc = {0.f, 0.f, 0.f, 0.f};
        #pragma unroll
        for (int kk = 0; kk < 6; ++kk) acc = mfma_bf16(a[kk], wf[t][kk], acc);
        const int nt = wv + 4 * t;
        if (OUT_F32) {
          const int col = nt * 16 + lr;
          #pragma unroll
          for (int j = 0; j < 4; ++j)
            ((float*)Ov)[(grow + j) * 192 + col] = acc[j] * scale + bcol[t];
        } else {
          const int hh = nt >> 1, c32 = (nt & 1) * 16 + lr;
          #pragma unroll
          for (int j = 0; j < 4; ++j)
            ((__bf16*)Ov)[((size_t)hh * ROWS + grow + j) * 32 + c32] =
                (__bf16)(acc[j] * scale + bcol[t]);
        }
      }
    }

    // write prefetched tile into the OTHER buffer; single barrier
    if (it < 5) {
      __bf16* wb = &Xs[((it + 1) & 1) * 12800];
      if (IN_F32) {
        #pragma unroll
        for (int p = 0; p < 12; ++p) {
          int i = tid + p * 256;
          int r = i / 48, c = i % 48;
          bf16x4 bb;
          bb[0] = (__bf16)pf[p][0]; bb[1] = (__bf16)pf[p][1];
          bb[2] = (__bf16)pf[p][2]; bb[3] = (__bf16)pf[p][3];
          *(bf16x4*)&wb[r * 200 + c * 4] = bb;
        }
      } else {
        #pragma unroll
        for (int p = 0; p < 6; ++p) {
          int i = tid + p * 256;
          int r = i / 24, c8 = i % 24;
          *(bf16x8*)&wb[r * 200 + c8 * 8] = pf8[p];
        }
      }
      __syncthreads();
    }
  }
}

// fused QKV: grid (ROWS/384 = 392, 3); y selects {q,k,v}
// Tripwires: WRITE >> 175MB -> spill; VGPR <= 110 -> compiler sank pf again.
__global__ __launch_bounds__(256, 1)
void qkvgemm(const float* __restrict__ xq, const float* __restrict__ xk,
             const float* __restrict__ xv,
             const __bf16* __restrict__ wq, const __bf16* __restrict__ wk,
             const __bf16* __restrict__ wv,
             const float* __restrict__ bq, const float* __restrict__ bk,
             const float* __restrict__ bv,
             __bf16* __restrict__ oq, __bf16* __restrict__ ok,
             __bf16* __restrict__ ov)
{
  __shared__ __align__(16) __bf16 Xs[2 * 12800];
  const int y = blockIdx.y;
  const float* x = y == 0 ? xq : y == 1 ? xk : xv;
  const __bf16* w = y == 0 ? wq : y == 1 ? wk : wv;
  const float* bi = y == 0 ? bq : y == 1 ? bk : bv;
  __bf16* o = y == 0 ? oq : y == 1 ? ok : ov;
  const float scale = y == 0 ? (QSCALE * L2E) : 1.f;
  gemm6t<true, false>(x, w, bi, o, scale, Xs);
}

// proj: head-major bf16 in, row-major f32 out; grid 392
__global__ __launch_bounds__(256, 1)
void projgemm(const __bf16* __restrict__ X, const __bf16* __restrict__ Wb,
              const float* __restrict__ bias, float* __restrict__ Ov)
{
  __shared__ __align__(16) __bf16 Xs[2 * 12800];
  gemm6t<false, true>(X, Wb, bias, Ov, 1.f, Xs);
}

// ---- attention v8 (round-10 proven, unchanged): head-major I/O, bm in LDS ----
__global__ __launch_bounds__(320, 5)
void attn8(const __bf16* __restrict__ Q, const __bf16* __restrict__ K,
           const __bf16* __restrict__ V, __bf16* __restrict__ O,
           const float* __restrict__ bmall)
{
  __shared__ __align__(16) __bf16 Ks[160 * 40];   // 12800 B, permuted rows
  __shared__ __align__(16) __bf16 Vt[32 * 168];   // 10752 B, [d][key pad168]
  __shared__ __align__(16) float bm2[2796];       // 11184 B, stride 57 (odd)

  const int b = blockIdx.x, h = blockIdx.y;
  const int tid = threadIdx.x;
  const size_t hb = (size_t)h * ROWS + (size_t)b * 147;  // head-major row base
  const int wv = tid >> 6, lane = tid & 63;
  const int lr = lane & 15, lg = lane >> 4;

  bf16x8 qf = *(const bf16x8*)&Q[(hb + wv * 16 + lr) * 32 + lg * 8];

  {
    const f4* bsrc = (const f4*)(bmall + (size_t)((b & 63) * 6 + h) * 2800);
    for (int i = tid; i < 699; i += 320) ((f4*)bm2)[i] = bsrc[i];
  }
  for (int i = tid; i < 588; i += 320) {          // K -> permuted rows
    int k = i >> 2, c = i & 3;
    int phys = (k & ~31) | (((k >> 2) & 1) << 4) | (((k >> 3) & 3) << 2) | (k & 3);
    *(bf16x8*)&Ks[phys * 40 + c * 8] = *(const bf16x8*)&K[(hb + k) * 32 + c * 8];
  }
  for (int t = tid; t < 588; t += 320) {          // V transpose scatter
    int key = t >> 2, dblk = t & 3;
    bf16x8 v = *(const bf16x8*)&V[(hb + key) * 32 + dblk * 8];
    #pragma unroll
    for (int e = 0; e < 8; ++e) Vt[(dblk * 8 + e) * 168 + key] = v[e];
  }
  for (int i = tid; i < 32 * 13; i += 320) {      // zero key tail 147..159
    int d = i / 13, key = 147 + (i - (i / 13) * 13);
    Vt[d * 168 + key] = (__bf16)0.f;
  }
  __syncthreads();

  #pragma unroll
  for (int t = 0; t < 2; ++t) {
    const int mt = wv + 5 * t;                     // waves cover mt 0..9 exactly

    bf16x8 qn = qf;
    if (t == 0) {
      int qr = (wv + 5) * 16 + lr; if (qr > 146) qr = 146;
      qn = *(const bf16x8*)&Q[(hb + qr) * 32 + lg * 8];
    }

    int r = mt * 16 + lr;
    int q49 = r; if (q49 >= 98) q49 -= 98; if (q49 >= 49) q49 -= 49;
    const float* bmrow = &bm2[q49 * 57];

    f32x4 o0 = {0.f,0.f,0.f,0.f}, o1 = {0.f,0.f,0.f,0.f};
    float sum = 0.f;
    int kb = lg * 8;                               // (32s + 8lg) % 49, incremental
    #pragma unroll
    for (int s = 0; s < 5; ++s) {
      const f32x4 z = {0.f,0.f,0.f,0.f};
      f32x4 st0 = mfma_bf16(*(const bf16x8*)&Ks[(s * 32 + lr) * 40 + lg * 8], qf, z);
      f32x4 st1 = mfma_bf16(*(const bf16x8*)&Ks[(s * 32 + 16 + lr) * 40 + lg * 8], qf, z);
      const float* bp = bmrow + kb;                // 8 consecutive f32 (row has 57)
      #pragma unroll
      for (int j = 0; j < 4; ++j) { st0[j] += bp[j]; st1[j] += bp[4 + j]; }
      if (s == 4) {                                // keys 128+8lg+j / 132+8lg+j >= 147
        #pragma unroll
        for (int j = 0; j < 4; ++j) {
          if (lg * 8 + j >= 19) st0[j] = -1e30f;
          if (lg * 8 + j >= 15) st1[j] = -1e30f;
        }
      }
      #pragma unroll
      for (int j = 0; j < 4; ++j) { st0[j] = exp2f(st0[j]); sum += st0[j]; }
      #pragma unroll
      for (int j = 0; j < 4; ++j) { st1[j] = exp2f(st1[j]); sum += st1[j]; }
      union { bf16x8 v; uint32_t w[4]; } pu;
      pu.w[0] = pack_bf16(st0[0], st0[1]);
      pu.w[1] = pack_bf16(st0[2], st0[3]);
      pu.w[2] = pack_bf16(st1[0], st1[1]);
      pu.w[3] = pack_bf16(st1[2], st1[3]);
      bf16x8 v0 = *(const bf16x8*)&Vt[lr * 168 + s * 32 + lg * 8];
      bf16x8 v1 = *(const bf16x8*)&Vt[(16 + lr) * 168 + s * 32 + lg * 8];
      o0 = mfma_bf16(pu.v, v0, o0);
      o1 = mfma_bf16(pu.v, v1, o1);
      kb += 32; if (kb >= 49) kb -= 49;            // stays in [0,49)
    }
    sum += __shfl_xor(sum, 16);
    sum += __shfl_xor(sum, 32);
    const float rinv = 1.f / sum;
    #pragma unroll
    for (int j = 0; j < 4; ++j) {
      const int qa = mt * 16 + lg * 4 + j;
      const float rj = __shfl(rinv, lg * 4 + j);   // row sums live at lanes 0..15
      if (qa < 147) {
        const size_t base = (hb + qa) * 32;
        O[base + lr]      = (__bf16)(o0[j] * rj);
        O[base + 16 + lr] = (__bf16)(o1[j] * rj);
      }
    }
    qf = qn;
  }
}

extern "C" void kernel_launch(void* const* d_in, const int* in_sizes, int n_in,
                              void* d_out, int out_size, void* d_ws, size_t ws_size,
                              hipStream_t stream) {
  (void)in_sizes; (void)n_in; (void)out_size;
  const float* x_q  = (const float*)d_in[0];
  const float* x_k  = (const float*)d_in[1];
  const float* x_v  = (const float*)d_in[2];
  const float* maskp= (const float*)d_in[3];
  const float* q_w  = (const float*)d_in[4];
  const float* q_b  = (const float*)d_in[5];
  const float* k_w  = (const float*)d_in[6];
  const float* k_b  = (const float*)d_in[7];
  const float* v_w  = (const float*)d_in[8];
  const float* v_b  = (const float*)d_in[9];
  const float* p_w  = (const float*)d_in[10];
  const float* p_b  = (const float*)d_in[11];
  const float* btab = (const float*)d_in[12];

  char* ws = (char*)d_ws;
  // [bmall 4.3MB][4 weights][qb][kb][vb][ob?]
  float* bmall = (float*)ws;
  const size_t bmsz = (size_t)64 * 6 * 2800 * sizeof(float);   // 4,300,800
  char* wsp = ws + bmsz;
  const size_t wsz = 36864 * sizeof(__bf16);
  __bf16* wq  = (__bf16*)wsp;
  __bf16* wk  = (__bf16*)(wsp + wsz);
  __bf16* wvp = (__bf16*)(wsp + 2 * wsz);
  __bf16* wp  = (__bf16*)(wsp + 3 * wsz);
  char* bufs = wsp + 4 * wsz;
  const size_t sz = (size_t)ROWS * 192 * sizeof(__bf16);       // 57.8 MB each
  __bf16* qb = (__bf16*)bufs;
  __bf16* kb = (__bf16*)(bufs + sz);
  __bf16* vb = (__bf16*)(bufs + 2 * sz);
  const size_t need4 = bmsz + 4 * wsz + 4 * sz;
  __bf16* ob = (ws_size >= need4) ? (__bf16*)(bufs + 3 * sz) : qb;

  prep<<<528, 256, 0, stream>>>(q_w, k_w, v_w, p_w, wq, wk, wvp, wp,
                                maskp, btab, bmall);

  // q pre-scaled by 1/sqrt(hd) AND log2(e) (exp2-direct softmax downstream)
  qkvgemm<<<dim3(ROWS / 384, 3), 256, 0, stream>>>(x_q, x_k, x_v, wq, wk, wvp,
                                                   q_b, k_b, v_b, qb, kb, vb);

  attn8<<<dim3(1024, 6), 320, 0, stream>>>(qb, kb, vb, ob, bmall);

  projgemm<<<ROWS / 384, 256, 0, stream>>>(ob, wp, p_b, (float*)d_out);
}